// Round 11
// baseline (205.781 us; speedup 1.0000x reference)
//
#include <hip/hip_runtime.h>
#include <hip/hip_bf16.h>
#include <math.h>

// Problem constants
#define Bb 4
#define Tt 1024
#define Cc 1024
#define Hh 16
#define Dd 64

typedef __attribute__((ext_vector_type(8))) _Float16 half8;
typedef __attribute__((ext_vector_type(4))) _Float16 half4;
typedef __attribute__((ext_vector_type(4))) float floatx4;

// Fragment-swizzled layout for an [R x 1024] f16 matrix:
//   addr(row,k) = (row>>4)*16384 + (k>>3)*128 + (row&15)*8 + (k&7)
// A wave's 16x16x32-MFMA operand fragment (rows 16-aligned, k 32-aligned) is
// base + lane*8 elems -> one coalesced global_load_dwordx4.

// ---------------------------------------------------------------------------
// prep_all: merged convert + weight-prep (one dispatch, saves a launch gap).
// blocks [0,256):    x fp32 [4096][1024] -> xh f16 frag-swizzled
// blocks [256,1280): W[z][1024][1024] fp32 -> Wt[z] f16 transposed+swizzled
// ---------------------------------------------------------------------------
struct PrepP { const float* x; _Float16* xh; const float* W[4]; _Float16* out[4]; };

__global__ __launch_bounds__(256) void prep_all(PrepP p)
{
    if (blockIdx.x < 256) {
        const int m16 = blockIdx.x;
        const int r   = threadIdx.x & 15;
        const int kc0 = threadIdx.x >> 4;
        const float* src = p.x + (size_t)(m16 * 16 + r) * 1024;
        _Float16*   dst = p.xh + (size_t)m16 * 16384 + r * 8;
#pragma unroll
        for (int c8 = 0; c8 < 8; ++c8) {
            const int kc = kc0 + c8 * 16;
            float4 a = *(const float4*)(src + kc * 8);
            float4 b = *(const float4*)(src + kc * 8 + 4);
            half8 h;
            h[0] = (_Float16)a.x; h[1] = (_Float16)a.y; h[2] = (_Float16)a.z; h[3] = (_Float16)a.w;
            h[4] = (_Float16)b.x; h[5] = (_Float16)b.y; h[6] = (_Float16)b.z; h[7] = (_Float16)b.w;
            *(half8*)(dst + kc * 128) = h;
        }
        return;
    }
    const int bid2 = blockIdx.x - 256;
    const int z    = bid2 >> 8;
    const int rem  = bid2 & 255;
    const int n0   = (rem & 15) * 64;
    const int k0   = (rem >> 4) * 64;
    const float* __restrict__ W = p.W[z];
    _Float16* __restrict__ outp = p.out[z];
    __shared__ float tile[64][65];
    const int tr  = threadIdx.x >> 4;
    const int tc4 = (threadIdx.x & 15) * 4;

#pragma unroll
    for (int i = 0; i < 4; ++i) {
        const int kk = tr + i * 16;
        float4 v = *(const float4*)(W + (size_t)(k0 + kk) * 1024 + n0 + tc4);
        tile[kk][tc4 + 0] = v.x;
        tile[kk][tc4 + 1] = v.y;
        tile[kk][tc4 + 2] = v.z;
        tile[kk][tc4 + 3] = v.w;
    }
    __syncthreads();
#pragma unroll
    for (int i = 0; i < 4; ++i) {
        half4 h;
#pragma unroll
        for (int c = 0; c < 4; ++c) h[c] = (_Float16)tile[tc4 + c][tr + i * 16];
        _Float16* dst = outp + (size_t)((n0 >> 4) + i) * 16384
                        + ((k0 + tc4) >> 3) * 128 + tr * 8 + (tc4 & 7);
        *(half4*)dst = h;
    }
}

// ---------------------------------------------------------------------------
// gemm_qkv: LDS-free frag-direct K-loop. ROUND 11: OPERAND SWAP for z<2 —
// A = Wt (m=col), B = xh (n=token) so the C-layout holds 4 consecutive d's
// per accumulator reg -> q/k epilogue is 16 half4 stores (was 64 scalar b16,
// the round-10 +2.7us regression). z=2 keeps m=token orientation (v's
// (d,t)-swizzle vectorizes over t).
// q/k per-bh (t,d)-frag: bh*65536 + (t>>4)*1024 + (d>>3)*128 + (t&15)*8+(d&7)
// v   per-bh (d,t)-frag: bh*65536 + (d>>4)*16384 + (t>>3)*128 + (d&15)*8+(t&7)
// Grid (32,8,3) x 256: blockIdx.x = token-tile always -> XCD-local x stripes.
// ---------------------------------------------------------------------------
struct QkvP { const _Float16* Wt[3]; const float* bias[3];
              _Float16* qb; _Float16* kb; _Float16* vt; };

__global__ __launch_bounds__(256) void gemm_qkv(const _Float16* __restrict__ xh, QkvP p)
{
    const int z = blockIdx.z;
    const float* __restrict__ bias = p.bias[z];

    const int tid  = threadIdx.x;
    const int lane = tid & 63;
    const int w    = tid >> 6;
    const int wr   = w >> 1, wc = w & 1;
    const int quad = lane >> 4;
    const int l15  = lane & 15;

    // m = rows of A, n = rows of B(^T). z<2: m=col(y), n=token(x); z=2 swapped.
    const int mb = (z == 2) ? blockIdx.x * 128 : blockIdx.y * 128;
    const int nb = (z == 2) ? blockIdx.y * 128 : blockIdx.x * 128;
    const _Float16* __restrict__ Abase = (z == 2) ? xh : p.Wt[z];
    const _Float16* __restrict__ Bbase = (z == 2) ? p.Wt[2] : xh;

    const _Float16* Ap[4];
    const _Float16* Bp[4];
#pragma unroll
    for (int i = 0; i < 4; ++i)
        Ap[i] = Abase + (size_t)((mb >> 4) + wr * 4 + i) * 16384 + lane * 8;
#pragma unroll
    for (int j = 0; j < 4; ++j)
        Bp[j] = Bbase + (size_t)((nb >> 4) + wc * 4 + j) * 16384 + lane * 8;

    floatx4 acc[4][4];
#pragma unroll
    for (int i = 0; i < 4; ++i)
#pragma unroll
        for (int j = 0; j < 4; ++j)
            acc[i][j] = (floatx4){0.f, 0.f, 0.f, 0.f};

    half8 a0[4], b0[4];
#pragma unroll
    for (int i = 0; i < 4; ++i) a0[i] = *(const half8*)(Ap[i]);
#pragma unroll
    for (int j = 0; j < 4; ++j) b0[j] = *(const half8*)(Bp[j]);

    for (int kt = 0; kt < 1024; kt += 64) {
        half8 a1[4], b1[4];
        const size_t o1 = (size_t)(kt + 32) * 16;
#pragma unroll
        for (int i = 0; i < 4; ++i) a1[i] = *(const half8*)(Ap[i] + o1);
#pragma unroll
        for (int j = 0; j < 4; ++j) b1[j] = *(const half8*)(Bp[j] + o1);
#pragma unroll
        for (int i = 0; i < 4; ++i)
#pragma unroll
            for (int j = 0; j < 4; ++j)
                acc[i][j] = __builtin_amdgcn_mfma_f32_16x16x32_f16(a0[i], b0[j], acc[i][j], 0, 0, 0);

        const size_t o2 = (kt + 64 < 1024) ? (size_t)(kt + 64) * 16 : 0;
#pragma unroll
        for (int i = 0; i < 4; ++i) a0[i] = *(const half8*)(Ap[i] + o2);
#pragma unroll
        for (int j = 0; j < 4; ++j) b0[j] = *(const half8*)(Bp[j] + o2);
#pragma unroll
        for (int i = 0; i < 4; ++i)
#pragma unroll
            for (int j = 0; j < 4; ++j)
                acc[i][j] = __builtin_amdgcn_mfma_f32_16x16x32_f16(a1[i], b1[j], acc[i][j], 0, 0, 0);
    }

    if (z == 2) {
        // v: m=token, n=col; half4 over 4 consecutive t
#pragma unroll
        for (int j = 0; j < 4; ++j) {
            const int col = nb + wc * 64 + j * 16 + l15;
            const int h  = col >> 6;
            const float bj = bias[col];
#pragma unroll
            for (int i = 0; i < 4; ++i) {
                const int t0 = mb + wr * 64 + i * 16 + quad * 4;
                const int bh = (t0 >> 10) * 16 + h;
                const int tm = t0 & 1023;
                half4 pk;
#pragma unroll
                for (int r = 0; r < 4; ++r) pk[r] = (_Float16)(acc[i][j][r] + bj);
                *(half4*)(p.vt + (size_t)bh * 65536 + (size_t)j * 16384
                          + (tm >> 3) * 128 + l15 * 8 + (tm & 7)) = pk;
            }
        }
    } else {
        // q/k: m=col, n=token; half4 over 4 consecutive d
        _Float16* outp = (z == 0) ? p.qb : p.kb;
#pragma unroll
        for (int j = 0; j < 4; ++j) {
            const int token = nb + wc * 64 + j * 16 + l15;
            const int bi = token >> 10;
            const int tm = token & 1023;
            const size_t tb = (size_t)(tm >> 4) * 1024 + (tm & 15) * 8;
#pragma unroll
            for (int i = 0; i < 4; ++i) {
                const int colb = mb + wr * 64 + i * 16 + quad * 4;
                const int h  = colb >> 6;
                const int d  = colb & 63;
                const float4 b4 = *(const float4*)(bias + colb);
                half4 pk;
                pk[0] = (_Float16)(acc[i][j][0] + b4.x);
                pk[1] = (_Float16)(acc[i][j][1] + b4.y);
                pk[2] = (_Float16)(acc[i][j][2] + b4.z);
                pk[3] = (_Float16)(acc[i][j][3] + b4.w);
                *(half4*)(outp + (size_t)(bi * 16 + h) * 65536 + tb
                          + (d >> 3) * 128 + (d & 7)) = pk;
            }
        }
    }
}

// ---------------------------------------------------------------------------
// attn_mfma ROUND 11: 512-thread blocks (8 waves x 16 q-rows) for 16 waves/CU
// (was 8 — latency-bound at 59%-busy TA). Barrier-free: frag-direct Q/K/V,
// wave-private P in LDS (2KB/wave), fixed-max softmax + ones-MFMA row sums.
// grid (64,8) x 512: x = bh -> XCD-local K/V.
// ---------------------------------------------------------------------------
__global__ __launch_bounds__(512) void attn_mfma(
    const _Float16* __restrict__ qb, const _Float16* __restrict__ kb,
    const _Float16* __restrict__ vt, const float* __restrict__ padj,
    _Float16* __restrict__ yh)
{
    __shared__ __align__(16) _Float16 Ps[8][1024];  // wave-private P [kc8][q16][8]

    const int tid  = threadIdx.x;
    const int lane = tid & 63;
    const int w    = tid >> 6;          // 0..7
    const int quad = lane >> 4;
    const int l15  = lane & 15;
    const int bh   = blockIdx.x;
    const int q0   = blockIdx.y * 128;
    const int b    = bh >> 4;
    const int h    = bh & 15;

    const _Float16* qf = qb + (size_t)bh * 65536;
    const _Float16* kf = kb + (size_t)bh * 65536;
    const _Float16* vf = vt + (size_t)bh * 65536;
    const float*    pk_row = padj + b * Tt;

    // Q frags: register-resident (wave's 16 q-rows), B-operand of S^T
    half8 bq[2];
#pragma unroll
    for (int ks = 0; ks < 2; ++ks)
        bq[ks] = *(const half8*)(qf + (size_t)((q0 >> 4) + w) * 1024 + ks * 512 + lane * 8);
    const float kq = 1.0f - pk_row[q0 + w * 16 + l15];

    floatx4 O[4];
    floatx4 l_acc = (floatx4){0.f, 0.f, 0.f, 0.f};
#pragma unroll
    for (int dj = 0; dj < 4; ++dj) O[dj] = (floatx4){0.f, 0.f, 0.f, 0.f};

    half8 ones;
#pragma unroll
    for (int j = 0; j < 8; ++j) ones[j] = (_Float16)1.0f;

    constexpr float SC = 0.18033688011112042f;  // 0.125 * log2(e)

    for (int kt = 0; kt < Tt; kt += 64) {
        // direct frag loads: K (A-op), V (B-op)
        half8 ak[2][4], bv[2][4];
#pragma unroll
        for (int ks = 0; ks < 2; ++ks)
#pragma unroll
            for (int mk = 0; mk < 4; ++mk)
                ak[ks][mk] = *(const half8*)(kf + (size_t)((kt >> 4) + mk) * 1024
                                             + ks * 512 + lane * 8);
#pragma unroll
        for (int ks = 0; ks < 2; ++ks)
#pragma unroll
            for (int dj = 0; dj < 4; ++dj)
                bv[ks][dj] = *(const half8*)(vf + (size_t)dj * 16384 + (kt >> 3) * 128
                                             + ks * 512 + lane * 8);
        float4 kk4[4];
#pragma unroll
        for (int mk = 0; mk < 4; ++mk)
            kk4[mk] = *(const float4*)(pk_row + kt + mk * 16 + quad * 4);

        // S^T = K Q^T : C[m=key(quad*4+r)][n=qrow(l15)]
        floatx4 ST[4];
#pragma unroll
        for (int mk = 0; mk < 4; ++mk) ST[mk] = (floatx4){0.f, 0.f, 0.f, 0.f};
#pragma unroll
        for (int ks = 0; ks < 2; ++ks)
#pragma unroll
            for (int mk = 0; mk < 4; ++mk)
                ST[mk] = __builtin_amdgcn_mfma_f32_16x16x32_f16(ak[ks][mk], bq[ks], ST[mk], 0, 0, 0);

        // fixed-max softmax + wave-private P write (conflict-free b64)
#pragma unroll
        for (int mk = 0; mk < 4; ++mk) {
            const float kkr[4] = {1.0f - kk4[mk].x, 1.0f - kk4[mk].y,
                                  1.0f - kk4[mk].z, 1.0f - kk4[mk].w};
            half4 pk;
#pragma unroll
            for (int r = 0; r < 4; ++r) {
                const float e = __builtin_amdgcn_exp2f(ST[mk][r] * SC);
                const float pv = (kq == 0.0f) ? 1.0f : kkr[r] * e;
                pk[r] = (_Float16)pv;
            }
            *(half4*)&Ps[w][((mk * 2 + (quad >> 1)) * 16 + l15) * 8 + (quad & 1) * 4] = pk;
        }
        // same-wave RAW on Ps -> compiler lgkmcnt; no barrier

        // O += P V ; l += P @ ones
#pragma unroll
        for (int ks = 0; ks < 2; ++ks) {
            half8 ap = *(const half8*)&Ps[w][((ks * 4 + quad) * 16 + l15) * 8];
#pragma unroll
            for (int dj = 0; dj < 4; ++dj)
                O[dj] = __builtin_amdgcn_mfma_f32_16x16x32_f16(ap, bv[ks][dj], O[dj], 0, 0, 0);
            l_acc = __builtin_amdgcn_mfma_f32_16x16x32_f16(ap, ones, l_acc, 0, 0, 0);
        }
    }

    // epilogue: normalize, write yh frag-swizzled (for LDS-free proj)
#pragma unroll
    for (int r = 0; r < 4; ++r) {
        const int rowl  = w * 16 + quad * 4 + r;
        const int token = b * Tt + q0 + rowl;
        const float inv = 1.0f / l_acc[r];
        const size_t tb = (size_t)(token >> 4) * 16384 + (token & 15) * 8;
#pragma unroll
        for (int dj = 0; dj < 4; ++dj) {
            const int col = h * 64 + dj * 16 + l15;
            yh[tb + (col >> 3) * 128 + (col & 7)] = (_Float16)(O[dj][r] * inv);
        }
    }
}

// ---------------------------------------------------------------------------
// gemm_proj: LDS-free frag-direct (round 9, verified). 128x64 tiles,
// grid (32,16) = 512 blocks, x = m-tile.
// ---------------------------------------------------------------------------
__global__ __launch_bounds__(256) void gemm_proj(const _Float16* __restrict__ Ay,
                                                 const _Float16* __restrict__ Bt,
                                                 const float* __restrict__ bias,
                                                 float* __restrict__ out)
{
    const int tid  = threadIdx.x;
    const int lane = tid & 63;
    const int w    = tid >> 6;
    const int quad = lane >> 4;
    const int l15  = lane & 15;
    const int bm   = blockIdx.x * 128;
    const int bn   = blockIdx.y * 64;

    const _Float16* Ap[2];
    const _Float16* Bp[4];
#pragma unroll
    for (int i = 0; i < 2; ++i)
        Ap[i] = Ay + (size_t)((bm >> 4) + w * 2 + i) * 16384 + lane * 8;
#pragma unroll
    for (int j = 0; j < 4; ++j)
        Bp[j] = Bt + (size_t)((bn >> 4) + j) * 16384 + lane * 8;

    floatx4 acc[2][4];
#pragma unroll
    for (int i = 0; i < 2; ++i)
#pragma unroll
        for (int j = 0; j < 4; ++j)
            acc[i][j] = (floatx4){0.f, 0.f, 0.f, 0.f};

    half8 a0[2], b0[4];
#pragma unroll
    for (int i = 0; i < 2; ++i) a0[i] = *(const half8*)(Ap[i]);
#pragma unroll
    for (int j = 0; j < 4; ++j) b0[j] = *(const half8*)(Bp[j]);

    for (int kt = 0; kt < 1024; kt += 64) {
        half8 a1[2], b1[4];
        const size_t o1 = (size_t)(kt + 32) * 16;
#pragma unroll
        for (int i = 0; i < 2; ++i) a1[i] = *(const half8*)(Ap[i] + o1);
#pragma unroll
        for (int j = 0; j < 4; ++j) b1[j] = *(const half8*)(Bp[j] + o1);
#pragma unroll
        for (int i = 0; i < 2; ++i)
#pragma unroll
            for (int j = 0; j < 4; ++j)
                acc[i][j] = __builtin_amdgcn_mfma_f32_16x16x32_f16(a0[i], b0[j], acc[i][j], 0, 0, 0);

        const size_t o2 = (kt + 64 < 1024) ? (size_t)(kt + 64) * 16 : 0;
#pragma unroll
        for (int i = 0; i < 2; ++i) a0[i] = *(const half8*)(Ap[i] + o2);
#pragma unroll
        for (int j = 0; j < 4; ++j) b0[j] = *(const half8*)(Bp[j] + o2);
#pragma unroll
        for (int i = 0; i < 2; ++i)
#pragma unroll
            for (int j = 0; j < 4; ++j)
                acc[i][j] = __builtin_amdgcn_mfma_f32_16x16x32_f16(a1[i], b1[j], acc[i][j], 0, 0, 0);
    }

#pragma unroll
    for (int j = 0; j < 4; ++j) {
        const int col = bn + j * 16 + l15;
        const float bj = bias[col];
#pragma unroll
        for (int i = 0; i < 2; ++i) {
            const int row = bm + w * 32 + i * 16 + quad * 4;
            float* o = out + (size_t)row * 1024 + col;
#pragma unroll
            for (int r = 0; r < 4; ++r)
                o[(size_t)r * 1024] = acc[i][j][r] + bj;
        }
    }
}

// ---------------------------------------------------------------------------
extern "C" void kernel_launch(void* const* d_in, const int* in_sizes, int n_in,
                              void* d_out, int out_size, void* d_ws, size_t ws_size,
                              hipStream_t stream)
{
    const float* x    = (const float*)d_in[0];
    const float* padj = (const float*)d_in[1];
    const float* Wq   = (const float*)d_in[2];
    const float* bq   = (const float*)d_in[3];
    const float* Wk   = (const float*)d_in[4];
    const float* bk   = (const float*)d_in[5];
    const float* Wv   = (const float*)d_in[6];
    const float* bv   = (const float*)d_in[7];
    const float* Wp   = (const float*)d_in[8];
    const float* bp   = (const float*)d_in[9];
    float* out = (float*)d_out;

    const size_t MB = 1024 * 1024;
    char* ws = (char*)d_ws;
    _Float16* xh  = (_Float16*)(ws);            //  8 MB (frag-swizzled)
    _Float16* Wt0 = (_Float16*)(ws +  8 * MB);  //  2 MB
    _Float16* Wt1 = (_Float16*)(ws + 10 * MB);  //  2 MB
    _Float16* Wt2 = (_Float16*)(ws + 12 * MB);  //  2 MB
    _Float16* Wtp = (_Float16*)(ws + 14 * MB);  //  2 MB
    _Float16* qb  = (_Float16*)(ws + 16 * MB);  //  8 MB (per-bh frag)
    _Float16* kb  = (_Float16*)(ws + 24 * MB);  //  8 MB (per-bh frag)
    _Float16* vtb = (_Float16*)(ws + 32 * MB);  //  8 MB (per-bh frag)
    _Float16* yh  = (_Float16*)(ws + 40 * MB);  //  8 MB (frag-swizzled) -> 48 MB

    PrepP pp;
    pp.x = x; pp.xh = xh;
    pp.W[0] = Wq; pp.W[1] = Wk; pp.W[2] = Wv; pp.W[3] = Wp;
    pp.out[0] = Wt0; pp.out[1] = Wt1; pp.out[2] = Wt2; pp.out[3] = Wtp;
    prep_all<<<1280, 256, 0, stream>>>(pp);

    QkvP qp;
    qp.Wt[0] = Wt0; qp.Wt[1] = Wt1; qp.Wt[2] = Wt2;
    qp.bias[0] = bq; qp.bias[1] = bk; qp.bias[2] = bv;
    qp.qb = qb; qp.kb = kb; qp.vt = vtb;
    gemm_qkv<<<dim3(32, 8, 3), 256, 0, stream>>>(xh, qp);

    attn_mfma<<<dim3(64, 8), 512, 0, stream>>>(qb, kb, vtb, padj, yh);

    gemm_proj<<<dim3(32, 16), 256, 0, stream>>>(yh, Wtp, bp, out);
}

// Round 12
// 186.956 us; speedup vs baseline: 1.1007x; 1.1007x over previous
//
#include <hip/hip_runtime.h>
#include <hip/hip_bf16.h>
#include <math.h>

// Problem constants
#define Bb 4
#define Tt 1024
#define Cc 1024
#define Hh 16
#define Dd 64

typedef __attribute__((ext_vector_type(8))) _Float16 half8;
typedef __attribute__((ext_vector_type(4))) _Float16 half4;
typedef __attribute__((ext_vector_type(4))) float floatx4;

// Fragment-swizzled layout for an [R x 1024] f16 matrix:
//   addr(row,k) = (row>>4)*16384 + (k>>3)*128 + (row&15)*8 + (k&7)
// A wave's 16x16x32-MFMA operand fragment (rows 16-aligned, k 32-aligned) is
// base + lane*8 elems -> one coalesced global_load_dwordx4.

// ---------------------------------------------------------------------------
// prep_all: merged convert + weight-prep (one dispatch; round-11 verified).
// blocks [0,256):    x fp32 [4096][1024] -> xh f16 frag-swizzled
// blocks [256,1280): W[z][1024][1024] fp32 -> Wt[z] f16 transposed+swizzled
// ---------------------------------------------------------------------------
struct PrepP { const float* x; _Float16* xh; const float* W[4]; _Float16* out[4]; };

__global__ __launch_bounds__(256) void prep_all(PrepP p)
{
    if (blockIdx.x < 256) {
        const int m16 = blockIdx.x;
        const int r   = threadIdx.x & 15;
        const int kc0 = threadIdx.x >> 4;
        const float* src = p.x + (size_t)(m16 * 16 + r) * 1024;
        _Float16*   dst = p.xh + (size_t)m16 * 16384 + r * 8;
#pragma unroll
        for (int c8 = 0; c8 < 8; ++c8) {
            const int kc = kc0 + c8 * 16;
            float4 a = *(const float4*)(src + kc * 8);
            float4 b = *(const float4*)(src + kc * 8 + 4);
            half8 h;
            h[0] = (_Float16)a.x; h[1] = (_Float16)a.y; h[2] = (_Float16)a.z; h[3] = (_Float16)a.w;
            h[4] = (_Float16)b.x; h[5] = (_Float16)b.y; h[6] = (_Float16)b.z; h[7] = (_Float16)b.w;
            *(half8*)(dst + kc * 128) = h;
        }
        return;
    }
    const int bid2 = blockIdx.x - 256;
    const int z    = bid2 >> 8;
    const int rem  = bid2 & 255;
    const int n0   = (rem & 15) * 64;
    const int k0   = (rem >> 4) * 64;
    const float* __restrict__ W = p.W[z];
    _Float16* __restrict__ outp = p.out[z];
    __shared__ float tile[64][65];
    const int tr  = threadIdx.x >> 4;
    const int tc4 = (threadIdx.x & 15) * 4;

#pragma unroll
    for (int i = 0; i < 4; ++i) {
        const int kk = tr + i * 16;
        float4 v = *(const float4*)(W + (size_t)(k0 + kk) * 1024 + n0 + tc4);
        tile[kk][tc4 + 0] = v.x;
        tile[kk][tc4 + 1] = v.y;
        tile[kk][tc4 + 2] = v.z;
        tile[kk][tc4 + 3] = v.w;
    }
    __syncthreads();
#pragma unroll
    for (int i = 0; i < 4; ++i) {
        half4 h;
#pragma unroll
        for (int c = 0; c < 4; ++c) h[c] = (_Float16)tile[tc4 + c][tr + i * 16];
        _Float16* dst = outp + (size_t)((n0 >> 4) + i) * 16384
                        + ((k0 + tc4) >> 3) * 128 + tr * 8 + (tc4 & 7);
        *(half4*)dst = h;
    }
}

// ---------------------------------------------------------------------------
// gemm_qkv: LDS-free frag-direct K-loop (round-10 configuration — verified
// best; round-11's operand swap regressed and was reverted). A = xh for all
// z (shared across z-siblings in L2), B = Wt[z].
// q/k per-bh (t,d)-frag: bh*65536 + (t>>4)*1024 + (d>>3)*128 + (t&15)*8+(d&7)
// v   per-bh (d,t)-frag: bh*65536 + (d>>4)*16384 + (t>>3)*128 + (d&15)*8+(t&7)
// Grid (32,8,3) x 256: blockIdx.x = token-tile -> XCD-local x stripes.
// ---------------------------------------------------------------------------
struct QkvP { const _Float16* Wt[3]; const float* bias[3];
              _Float16* qb; _Float16* kb; _Float16* vt; };

__global__ __launch_bounds__(256) void gemm_qkv(const _Float16* __restrict__ xh, QkvP p)
{
    const int z = blockIdx.z;
    const _Float16* __restrict__ Wt   = p.Wt[z];
    const float* __restrict__    bias = p.bias[z];

    const int tid  = threadIdx.x;
    const int lane = tid & 63;
    const int w    = tid >> 6;
    const int wr   = w >> 1, wc = w & 1;
    const int quad = lane >> 4;
    const int l15  = lane & 15;
    const int bm   = blockIdx.x * 128;
    const int bn   = blockIdx.y * 128;

    const _Float16* Ap[4];
    const _Float16* Bp[4];
#pragma unroll
    for (int i = 0; i < 4; ++i)
        Ap[i] = xh + (size_t)((bm >> 4) + wr * 4 + i) * 16384 + lane * 8;
#pragma unroll
    for (int j = 0; j < 4; ++j)
        Bp[j] = Wt + (size_t)((bn >> 4) + wc * 4 + j) * 16384 + lane * 8;

    floatx4 acc[4][4];
#pragma unroll
    for (int i = 0; i < 4; ++i)
#pragma unroll
        for (int j = 0; j < 4; ++j)
            acc[i][j] = (floatx4){0.f, 0.f, 0.f, 0.f};

    half8 a0[4], b0[4];
#pragma unroll
    for (int i = 0; i < 4; ++i) a0[i] = *(const half8*)(Ap[i]);
#pragma unroll
    for (int j = 0; j < 4; ++j) b0[j] = *(const half8*)(Bp[j]);

    for (int kt = 0; kt < 1024; kt += 64) {
        half8 a1[4], b1[4];
        const size_t o1 = (size_t)(kt + 32) * 16;
#pragma unroll
        for (int i = 0; i < 4; ++i) a1[i] = *(const half8*)(Ap[i] + o1);
#pragma unroll
        for (int j = 0; j < 4; ++j) b1[j] = *(const half8*)(Bp[j] + o1);
#pragma unroll
        for (int i = 0; i < 4; ++i)
#pragma unroll
            for (int j = 0; j < 4; ++j)
                acc[i][j] = __builtin_amdgcn_mfma_f32_16x16x32_f16(a0[i], b0[j], acc[i][j], 0, 0, 0);

        const size_t o2 = (kt + 64 < 1024) ? (size_t)(kt + 64) * 16 : 0;
#pragma unroll
        for (int i = 0; i < 4; ++i) a0[i] = *(const half8*)(Ap[i] + o2);
#pragma unroll
        for (int j = 0; j < 4; ++j) b0[j] = *(const half8*)(Bp[j] + o2);
#pragma unroll
        for (int i = 0; i < 4; ++i)
#pragma unroll
            for (int j = 0; j < 4; ++j)
                acc[i][j] = __builtin_amdgcn_mfma_f32_16x16x32_f16(a1[i], b1[j], acc[i][j], 0, 0, 0);
    }

    if (z == 2) {
        // v -> per-bh (d,t) frag-swizzle; 4 consecutive t at fixed d = half4
#pragma unroll
        for (int j = 0; j < 4; ++j) {
            const int col = bn + wc * 64 + j * 16 + l15;
            const int h  = col >> 6;
            const float bj = bias[col];
#pragma unroll
            for (int i = 0; i < 4; ++i) {
                const int t0 = bm + wr * 64 + i * 16 + quad * 4;
                const int bh = (t0 >> 10) * 16 + h;
                const int tm = t0 & 1023;
                half4 pk;
#pragma unroll
                for (int r = 0; r < 4; ++r) pk[r] = (_Float16)(acc[i][j][r] + bj);
                *(half4*)(p.vt + (size_t)bh * 65536 + (size_t)j * 16384
                          + (tm >> 3) * 128 + l15 * 8 + (tm & 7)) = pk;
            }
        }
    } else {
        // q/k -> per-bh (t,d) frag-swizzle
        _Float16* outp = (z == 0) ? p.qb : p.kb;
#pragma unroll
        for (int j = 0; j < 4; ++j) {
            const int col = bn + wc * 64 + j * 16 + l15;
            const int h  = col >> 6;
            const int dd = col & 63;
            const float bj = bias[col];
            const int doff = (dd >> 3) * 128 + (dd & 7);
#pragma unroll
            for (int i = 0; i < 4; ++i) {
#pragma unroll
                for (int r = 0; r < 4; ++r) {
                    const int tg = bm + wr * 64 + i * 16 + quad * 4 + r;
                    const int bh = (tg >> 10) * 16 + h;
                    const int tm = tg & 1023;
                    outp[(size_t)bh * 65536 + (tm >> 4) * 1024 + doff + (tm & 15) * 8] =
                        (_Float16)(acc[i][j][r] + bj);
                }
            }
        }
    }
}

// ---------------------------------------------------------------------------
// attn_mfma (round-10 configuration — verified; round-11's 512-thread variant
// doubled K/V traffic and regressed). BARRIER-FREE: frag-direct Q/K/V loads,
// wave-private P in LDS, fixed-max softmax + ones-MFMA row sums.
// 4 waves x 32 q-rows, 128 q-rows/block; grid (64,8) x 256: x = bh.
// ---------------------------------------------------------------------------
__global__ __launch_bounds__(256) void attn_mfma(
    const _Float16* __restrict__ qb, const _Float16* __restrict__ kb,
    const _Float16* __restrict__ vt, const float* __restrict__ padj,
    _Float16* __restrict__ yh)
{
    __shared__ __align__(16) _Float16 Ps[4][2048];  // wave-private P

    const int tid  = threadIdx.x;
    const int lane = tid & 63;
    const int w    = tid >> 6;
    const int quad = lane >> 4;
    const int l15  = lane & 15;
    const int bh   = blockIdx.x;
    const int q0   = blockIdx.y * 128;
    const int b    = bh >> 4;
    const int h    = bh & 15;

    const _Float16* qf = qb + (size_t)bh * 65536;
    const _Float16* kf = kb + (size_t)bh * 65536;
    const _Float16* vf = vt + (size_t)bh * 65536;
    const float*    pk_row = padj + b * Tt;

    // Q frags: register-resident for entire K-loop (B-operand of S^T)
    half8 bq[2][2];
#pragma unroll
    for (int ks = 0; ks < 2; ++ks)
#pragma unroll
        for (int nq = 0; nq < 2; ++nq)
            bq[ks][nq] = *(const half8*)(qf + (size_t)((q0 >> 4) + w * 2 + nq) * 1024
                                         + ks * 512 + lane * 8);
    float kq[2];
#pragma unroll
    for (int nq = 0; nq < 2; ++nq)
        kq[nq] = 1.0f - pk_row[q0 + w * 32 + nq * 16 + l15];

    floatx4 O[2][4];
    floatx4 l_acc[2];
#pragma unroll
    for (int mi = 0; mi < 2; ++mi) {
#pragma unroll
        for (int dj = 0; dj < 4; ++dj) O[mi][dj] = (floatx4){0.f, 0.f, 0.f, 0.f};
        l_acc[mi] = (floatx4){0.f, 0.f, 0.f, 0.f};
    }
    half8 ones;
#pragma unroll
    for (int j = 0; j < 8; ++j) ones[j] = (_Float16)1.0f;

    constexpr float SC = 0.18033688011112042f;  // 0.125 * log2(e)

    for (int kt = 0; kt < Tt; kt += 64) {
        // direct frag loads: K (A-operand), V (B-operand)
        half8 ak[2][4], bv[2][4];
#pragma unroll
        for (int ks = 0; ks < 2; ++ks)
#pragma unroll
            for (int mk = 0; mk < 4; ++mk)
                ak[ks][mk] = *(const half8*)(kf + (size_t)((kt >> 4) + mk) * 1024
                                             + ks * 512 + lane * 8);
#pragma unroll
        for (int ks = 0; ks < 2; ++ks)
#pragma unroll
            for (int dj = 0; dj < 4; ++dj)
                bv[ks][dj] = *(const half8*)(vf + (size_t)dj * 16384 + (kt >> 3) * 128
                                             + ks * 512 + lane * 8);
        float4 kk4[4];
#pragma unroll
        for (int mk = 0; mk < 4; ++mk)
            kk4[mk] = *(const float4*)(pk_row + kt + mk * 16 + quad * 4);

        // S^T = K Q^T : C[m=key(quad*4+r)][n=qrow(l15)]
        floatx4 ST[4][2];
#pragma unroll
        for (int mk = 0; mk < 4; ++mk)
#pragma unroll
            for (int nq = 0; nq < 2; ++nq)
                ST[mk][nq] = (floatx4){0.f, 0.f, 0.f, 0.f};
#pragma unroll
        for (int ks = 0; ks < 2; ++ks)
#pragma unroll
            for (int mk = 0; mk < 4; ++mk)
#pragma unroll
                for (int nq = 0; nq < 2; ++nq)
                    ST[mk][nq] = __builtin_amdgcn_mfma_f32_16x16x32_f16(
                        ak[ks][mk], bq[ks][nq], ST[mk][nq], 0, 0, 0);

        // fixed-max softmax + wave-private P write (conflict-free b64)
#pragma unroll
        for (int mk = 0; mk < 4; ++mk) {
            const float kkr[4] = {1.0f - kk4[mk].x, 1.0f - kk4[mk].y,
                                  1.0f - kk4[mk].z, 1.0f - kk4[mk].w};
#pragma unroll
            for (int nq = 0; nq < 2; ++nq) {
                half4 pk;
#pragma unroll
                for (int r = 0; r < 4; ++r) {
                    const float e = __builtin_amdgcn_exp2f(ST[mk][nq][r] * SC);
                    const float pv = (kq[nq] == 0.0f) ? 1.0f : kkr[r] * e;
                    pk[r] = (_Float16)pv;
                }
                *(half4*)&Ps[w][((mk * 2 + (quad >> 1)) * 32 + nq * 16 + l15) * 8
                               + (quad & 1) * 4] = pk;
            }
        }
        // same-wave RAW on Ps -> compiler lgkmcnt; no barrier needed

        // O += P V ; l += P @ ones
#pragma unroll
        for (int ks = 0; ks < 2; ++ks) {
            half8 ap[2];
#pragma unroll
            for (int mi = 0; mi < 2; ++mi)
                ap[mi] = *(const half8*)&Ps[w][((ks * 4 + quad) * 32 + mi * 16 + l15) * 8];
#pragma unroll
            for (int mi = 0; mi < 2; ++mi) {
#pragma unroll
                for (int dj = 0; dj < 4; ++dj)
                    O[mi][dj] = __builtin_amdgcn_mfma_f32_16x16x32_f16(
                        ap[mi], bv[ks][dj], O[mi][dj], 0, 0, 0);
                l_acc[mi] = __builtin_amdgcn_mfma_f32_16x16x32_f16(
                    ap[mi], ones, l_acc[mi], 0, 0, 0);
            }
        }
    }

    // epilogue: normalize, write yh frag-swizzled (for LDS-free proj)
#pragma unroll
    for (int mi = 0; mi < 2; ++mi) {
#pragma unroll
        for (int r = 0; r < 4; ++r) {
            const int rowl  = w * 32 + mi * 16 + quad * 4 + r;
            const int token = b * Tt + q0 + rowl;
            const float inv = 1.0f / l_acc[mi][r];
            const size_t tb = (size_t)(token >> 4) * 16384 + (token & 15) * 8;
#pragma unroll
            for (int dj = 0; dj < 4; ++dj) {
                const int col = h * 64 + dj * 16 + l15;
                yh[tb + (col >> 3) * 128 + (col & 7)] = (_Float16)(O[mi][dj][r] * inv);
            }
        }
    }
}

// ---------------------------------------------------------------------------
// gemm_proj: LDS-free frag-direct (round 9/10, verified). 128x64 tiles,
// grid (32,16) = 512 blocks, x = m-tile.
// ---------------------------------------------------------------------------
__global__ __launch_bounds__(256) void gemm_proj(const _Float16* __restrict__ Ay,
                                                 const _Float16* __restrict__ Bt,
                                                 const float* __restrict__ bias,
                                                 float* __restrict__ out)
{
    const int tid  = threadIdx.x;
    const int lane = tid & 63;
    const int w    = tid >> 6;
    const int quad = lane >> 4;
    const int l15  = lane & 15;
    const int bm   = blockIdx.x * 128;
    const int bn   = blockIdx.y * 64;

    const _Float16* Ap[2];
    const _Float16* Bp[4];
#pragma unroll
    for (int i = 0; i < 2; ++i)
        Ap[i] = Ay + (size_t)((bm >> 4) + w * 2 + i) * 16384 + lane * 8;
#pragma unroll
    for (int j = 0; j < 4; ++j)
        Bp[j] = Bt + (size_t)((bn >> 4) + j) * 16384 + lane * 8;

    floatx4 acc[2][4];
#pragma unroll
    for (int i = 0; i < 2; ++i)
#pragma unroll
        for (int j = 0; j < 4; ++j)
            acc[i][j] = (floatx4){0.f, 0.f, 0.f, 0.f};

    half8 a0[2], b0[4];
#pragma unroll
    for (int i = 0; i < 2; ++i) a0[i] = *(const half8*)(Ap[i]);
#pragma unroll
    for (int j = 0; j < 4; ++j) b0[j] = *(const half8*)(Bp[j]);

    for (int kt = 0; kt < 1024; kt += 64) {
        half8 a1[2], b1[4];
        const size_t o1 = (size_t)(kt + 32) * 16;
#pragma unroll
        for (int i = 0; i < 2; ++i) a1[i] = *(const half8*)(Ap[i] + o1);
#pragma unroll
        for (int j = 0; j < 4; ++j) b1[j] = *(const half8*)(Bp[j] + o1);
#pragma unroll
        for (int i = 0; i < 2; ++i)
#pragma unroll
            for (int j = 0; j < 4; ++j)
                acc[i][j] = __builtin_amdgcn_mfma_f32_16x16x32_f16(a0[i], b0[j], acc[i][j], 0, 0, 0);

        const size_t o2 = (kt + 64 < 1024) ? (size_t)(kt + 64) * 16 : 0;
#pragma unroll
        for (int i = 0; i < 2; ++i) a0[i] = *(const half8*)(Ap[i] + o2);
#pragma unroll
        for (int j = 0; j < 4; ++j) b0[j] = *(const half8*)(Bp[j] + o2);
#pragma unroll
        for (int i = 0; i < 2; ++i)
#pragma unroll
            for (int j = 0; j < 4; ++j)
                acc[i][j] = __builtin_amdgcn_mfma_f32_16x16x32_f16(a1[i], b1[j], acc[i][j], 0, 0, 0);
    }

#pragma unroll
    for (int j = 0; j < 4; ++j) {
        const int col = bn + j * 16 + l15;
        const float bj = bias[col];
#pragma unroll
        for (int i = 0; i < 2; ++i) {
            const int row = bm + w * 32 + i * 16 + quad * 4;
            float* o = out + (size_t)row * 1024 + col;
#pragma unroll
            for (int r = 0; r < 4; ++r)
                o[(size_t)r * 1024] = acc[i][j][r] + bj;
        }
    }
}

// ---------------------------------------------------------------------------
extern "C" void kernel_launch(void* const* d_in, const int* in_sizes, int n_in,
                              void* d_out, int out_size, void* d_ws, size_t ws_size,
                              hipStream_t stream)
{
    const float* x    = (const float*)d_in[0];
    const float* padj = (const float*)d_in[1];
    const float* Wq   = (const float*)d_in[2];
    const float* bq   = (const float*)d_in[3];
    const float* Wk   = (const float*)d_in[4];
    const float* bk   = (const float*)d_in[5];
    const float* Wv   = (const float*)d_in[6];
    const float* bv   = (const float*)d_in[7];
    const float* Wp   = (const float*)d_in[8];
    const float* bp   = (const float*)d_in[9];
    float* out = (float*)d_out;

    const size_t MB = 1024 * 1024;
    char* ws = (char*)d_ws;
    _Float16* xh  = (_Float16*)(ws);            //  8 MB (frag-swizzled)
    _Float16* Wt0 = (_Float16*)(ws +  8 * MB);  //  2 MB
    _Float16* Wt1 = (_Float16*)(ws + 10 * MB);  //  2 MB
    _Float16* Wt2 = (_Float16*)(ws + 12 * MB);  //  2 MB
    _Float16* Wtp = (_Float16*)(ws + 14 * MB);  //  2 MB
    _Float16* qb  = (_Float16*)(ws + 16 * MB);  //  8 MB (per-bh frag)
    _Float16* kb  = (_Float16*)(ws + 24 * MB);  //  8 MB (per-bh frag)
    _Float16* vtb = (_Float16*)(ws + 32 * MB);  //  8 MB (per-bh frag)
    _Float16* yh  = (_Float16*)(ws + 40 * MB);  //  8 MB (frag-swizzled) -> 48 MB

    PrepP pp;
    pp.x = x; pp.xh = xh;
    pp.W[0] = Wq; pp.W[1] = Wk; pp.W[2] = Wv; pp.W[3] = Wp;
    pp.out[0] = Wt0; pp.out[1] = Wt1; pp.out[2] = Wt2; pp.out[3] = Wtp;
    prep_all<<<1280, 256, 0, stream>>>(pp);

    QkvP qp;
    qp.Wt[0] = Wt0; qp.Wt[1] = Wt1; qp.Wt[2] = Wt2;
    qp.bias[0] = bq; qp.bias[1] = bk; qp.bias[2] = bv;
    qp.qb = qb; qp.kb = kb; qp.vt = vtb;
    gemm_qkv<<<dim3(32, 8, 3), 256, 0, stream>>>(xh, qp);

    attn_mfma<<<dim3(64, 8), 256, 0, stream>>>(qb, kb, vtb, padj, yh);

    gemm_proj<<<dim3(32, 16), 256, 0, stream>>>(yh, Wtp, bp, out);
}